// Round 8
// baseline (304.006 us; speedup 1.0000x reference)
//
#include <hip/hip_runtime.h>
#include <hip/hip_bf16.h>

// GCN: 3 layers of  h = h + relu( segment_sum( norm * (h@W^T+b)[row], col ) )
// norm[e] = dis[row]*dis[col]*(row!=col), dis[v] = deg_row(v)>0 ? rsqrt(deg) : 0
// N=50000, D=128, E=800000. Harness compares in bf16 space (threshold 0.108):
// hW / GEMM inputs carried in bf16, accumulation fp32.
//
// R19: edge-scan loops UNROLLED x4 with batched loads. R18 profile: hist
// 46us @ 13% HBM / 7.5% VALU / 18% occ with ALL occupancy+traffic levers
// exhausted => per-wave instruction-level serialization: the `continue`+
// atomic loop body blocks pipelining, each of ~24 iters/thread exposes full
// memory latency with only 2 loads in flight. Fix: batch 4 row/col pairs (8
// independent loads) per round; scatter additionally hoists the 8 dis
// gathers out of the predicate (dis is L2-resident, extra gathers cheap).
// Predicated processing unchanged.
// R18 (kept): L0 GEMM fused into hist y=5 (neutral but -1 dispatch).
// R17 (kept): CHUNKS=128; scatter quarter-split (12.5KB); agg index-clamp.
// R15 (kept): hist half-split (25KB LDS).
// R12/R11 (kept): agg 16 edges/round quad-row gathers, shfl_xor reduce.
// Kept lessons: no cooperative fusion (R7); global atomics contention-bound
// (R14); predicated gathers lose to clamped in agg (R16); partials traffic
// not binding (R17).

#define D_DIM 128
#define SCAN_CHUNK 1024
#define CHUNKS 128         // edge chunks
#define GROUPS 8
#define GS (CHUNKS / GROUPS)   // 16 chunks per group
#define LDSW 12512         // packed words: 4 bins/word -> 50048 bins >= N
#define HALVES 2
#define HWRD (LDSW / HALVES)   // 6256 words per half (25KB LDS) -- hist
#define HBINS (HWRD * 4)       // 25024 bins per half
#define QUARTERS 4
#define QWRD (LDSW / QUARTERS) // 3128 words per quarter (12.5KB LDS) -- scatter
#define QBINS (QWRD * 4)       // 12512 bins per quarter

typedef __attribute__((ext_vector_type(8))) short bf16x8;
typedef __attribute__((ext_vector_type(4))) float f32x4;

static __device__ __forceinline__ short f2bf(float f) {
    union { __hip_bfloat16 b; short s; } u;
    u.b = __float2bfloat16(f);
    return u.s;
}
static __device__ __forceinline__ float bf_lo(unsigned p) { return __uint_as_float(p << 16); }
static __device__ __forceinline__ float bf_hi(unsigned p) { return __uint_as_float(p & 0xffff0000u); }

// ---------------- CSR build (no global atomics, packed u8) ------------------

// grid (782, 6): y=0/1 col hist half 0/1, y=2/3 row hist half 0/1 (ch<CHUNKS),
// y=4 W->bf16 convert (<192 blocks), y=5 fused layer-0 linear (782 blocks).
// All paths share one 25KB LDS allocation (GEMM stages in an alias of it).
__global__ __launch_bounds__(256) void hist_kernel(const int* __restrict__ ei,
                                                   unsigned* __restrict__ partial_col,
                                                   unsigned* __restrict__ partial_row,
                                                   const float* __restrict__ W0,
                                                   const float* __restrict__ W1,
                                                   const float* __restrict__ W2,
                                                   unsigned short* __restrict__ Wb,
                                                   const float* __restrict__ x,
                                                   const float* __restrict__ b0,
                                                   unsigned short* __restrict__ hWb,
                                                   int nrows, int E, int CHSZ) {
    __shared__ unsigned hh[HWRD];
    int tid = threadIdx.x;
    if (blockIdx.y == 4) {                          // wcvt slice: 3*16384 elems
        int i = blockIdx.x * 256 + tid;
        if (i < 3 * D_DIM * D_DIM) {
            const float* W = (i < 16384) ? W0 : (i < 32768) ? W1 : W2;
            Wb[i] = (unsigned short)f2bf(W[i & 16383]);
        }
        return;
    }
    if (blockIdx.y == 5) {                          // fused layer-0 linear
        int wave = tid >> 6;
        int lane = tid & 63;
        int r0 = blockIdx.x * 64 + wave * 16;
        if (r0 >= nrows) return;
        int m = lane & 15, q = lane >> 4;
        int rload = min(r0 + m, nrows - 1);
        const float4* h4 = (const float4*)x;
        const float4* w4 = (const float4*)W0;

        f32x4 acc[8];
#pragma unroll
        for (int jt = 0; jt < 8; jt++) acc[jt] = (f32x4){0.f, 0.f, 0.f, 0.f};

#pragma unroll
        for (int k0 = 0; k0 < 128; k0 += 32) {
            int c0 = k0 + q * 8;
            float4 x0 = h4[rload * 32 + (c0 >> 2)];
            float4 x1 = h4[rload * 32 + (c0 >> 2) + 1];
            bf16x8 a;
            a[0] = f2bf(x0.x); a[1] = f2bf(x0.y); a[2] = f2bf(x0.z); a[3] = f2bf(x0.w);
            a[4] = f2bf(x1.x); a[5] = f2bf(x1.y); a[6] = f2bf(x1.z); a[7] = f2bf(x1.w);
#pragma unroll
            for (int jt = 0; jt < 8; jt++) {
                float4 w0v = w4[(jt * 16 + m) * 32 + (c0 >> 2)];
                float4 w1v = w4[(jt * 16 + m) * 32 + (c0 >> 2) + 1];
                bf16x8 b;
                b[0] = f2bf(w0v.x); b[1] = f2bf(w0v.y); b[2] = f2bf(w0v.z); b[3] = f2bf(w0v.w);
                b[4] = f2bf(w1v.x); b[5] = f2bf(w1v.y); b[6] = f2bf(w1v.z); b[7] = f2bf(w1v.w);
                acc[jt] = __builtin_amdgcn_mfma_f32_16x16x32_bf16(a, b, acc[jt], 0, 0, 0);
            }
        }
        unsigned short* stg = (unsigned short*)hh + wave * 16 * 136;  // LDS alias
#pragma unroll
        for (int jt = 0; jt < 8; jt++) {
            float bv = b0[jt * 16 + m];
#pragma unroll
            for (int reg = 0; reg < 4; reg++)
                stg[(q * 4 + reg) * 136 + jt * 16 + m] =
                    (unsigned short)f2bf(acc[jt][reg] + bv);
        }
#pragma unroll
        for (int t = 0; t < 4; t++) {
            int rl = t * 4 + (lane >> 4);
            int gr = r0 + rl;
            if (gr < nrows) {
                uint4 v = *(const uint4*)&stg[rl * 136 + (lane & 15) * 8];
                *(uint4*)&hWb[(size_t)gr * D_DIM + (lane & 15) * 8] = v;
            }
        }
        return;
    }
    int ch = blockIdx.x;
    if (ch >= CHUNKS) return;                       // grid.x widened for y>=4
    int docol = (blockIdx.y < 2);
    int half = blockIdx.y & 1;
    int bin0 = half * HBINS;
    for (int i = tid; i < HWRD; i += 256) hh[i] = 0u;
    __syncthreads();
    int e0 = ch * CHSZ, e1 = min(e0 + CHSZ, E);
    int e = e0 + tid;
    // R19: unroll x4, batch the 8 independent ei loads before processing
    for (; e + 768 < e1; e += 1024) {
        int r0 = ei[e],       c0 = ei[E + e];
        int r1 = ei[e + 256], c1 = ei[E + e + 256];
        int r2 = ei[e + 512], c2 = ei[E + e + 512];
        int r3 = ei[e + 768], c3 = ei[E + e + 768];
        int b0_ = (docol ? c0 : r0) - bin0;
        int b1_ = (docol ? c1 : r1) - bin0;
        int b2_ = (docol ? c2 : r2) - bin0;
        int b3_ = (docol ? c3 : r3) - bin0;
        if (r0 != c0 && (unsigned)b0_ < (unsigned)HBINS)
            atomicAdd(&hh[b0_ >> 2], 1u << ((b0_ & 3) * 8));
        if (r1 != c1 && (unsigned)b1_ < (unsigned)HBINS)
            atomicAdd(&hh[b1_ >> 2], 1u << ((b1_ & 3) * 8));
        if (r2 != c2 && (unsigned)b2_ < (unsigned)HBINS)
            atomicAdd(&hh[b2_ >> 2], 1u << ((b2_ & 3) * 8));
        if (r3 != c3 && (unsigned)b3_ < (unsigned)HBINS)
            atomicAdd(&hh[b3_ >> 2], 1u << ((b3_ & 3) * 8));
    }
    for (; e < e1; e += 256) {
        int row = ei[e];
        int col = ei[E + e];
        if (row == col) continue;                  // remove_self_loops
        int rb = (docol ? col : row) - bin0;
        if ((unsigned)rb < (unsigned)HBINS)
            atomicAdd(&hh[rb >> 2], 1u << ((rb & 3) * 8));
    }
    __syncthreads();
    unsigned* dst = (docol ? partial_col : partial_row) + (size_t)ch * LDSW + half * HWRD;
    for (int i = tid; i < HWRD; i += 256) dst[i] = hh[i];
}

// grid (ceil(NW/256), GROUPS, 2). z=0: in-place exclusive prefix of col counts
// over the group's GS chunks + group sum. z=1: row group sums only.
__global__ __launch_bounds__(256) void group_prefix_kernel(
    unsigned* __restrict__ partial_col, const unsigned* __restrict__ partial_row,
    unsigned* __restrict__ gsum_col, unsigned* __restrict__ gsum_row, int NW) {
    int w = blockIdx.x * 256 + threadIdx.x;
    if (w >= NW) return;
    int g = blockIdx.y;
    size_t base = (size_t)(g * GS) * LDSW + w;
    if (blockIdx.z == 0) {
        unsigned run = 0;
#pragma unroll 4
        for (int c = 0; c < GS; c++) {
            unsigned v = partial_col[base + (size_t)c * LDSW];
            partial_col[base + (size_t)c * LDSW] = run;
            run += v;
        }
        gsum_col[g * NW + w] = run;
    } else {
        unsigned run = 0;
#pragma unroll 4
        for (int c = 0; c < GS; c++) run += partial_row[base + (size_t)c * LDSW];
        gsum_row[g * NW + w] = run;
    }
}

// per packed word: sum the GROUPS group words -> col_cnt int4, dis float4,
// per-SCAN_CHUNK block sums, AND in-place exclusive prefix of gsum_col over
// groups (values already in registers -- replaces the gpref launch).
__global__ __launch_bounds__(256) void cnt_dis_kernel(
    unsigned* __restrict__ gsum_col, const unsigned* __restrict__ gsum_row,
    int* __restrict__ col_cnt, float* __restrict__ dis, int* __restrict__ bsum, int NW) {
    __shared__ int wsum[4];
    int w = blockIdx.x * 256 + threadIdx.x;
    int s = 0;
    if (w < NW) {
        unsigned wcv[GROUPS];
        unsigned clo = 0, chi = 0, rlo = 0, rhi = 0;
#pragma unroll
        for (int g = 0; g < GROUPS; g++) {
            unsigned wc = gsum_col[g * NW + w];
            unsigned wr = gsum_row[g * NW + w];
            wcv[g] = wc;
            clo += wc & 0x00FF00FFu; chi += (wc >> 8) & 0x00FF00FFu;
            rlo += wr & 0x00FF00FFu; rhi += (wr >> 8) & 0x00FF00FFu;
        }
        unsigned run = 0;
#pragma unroll
        for (int g = 0; g < GROUPS; g++) {         // exclusive prefix (packed u8)
            gsum_col[g * NW + w] = run;
            run += wcv[g];
        }
        int c0 = clo & 0xFFFF, c1 = chi & 0xFFFF, c2 = clo >> 16, c3 = chi >> 16;
        int r0 = rlo & 0xFFFF, r1 = rhi & 0xFFFF, r2 = rlo >> 16, r3 = rhi >> 16;
        ((int4*)col_cnt)[w] = make_int4(c0, c1, c2, c3);
        float4 dv;
        dv.x = (r0 > 0) ? rsqrtf((float)r0) : 0.0f;
        dv.y = (r1 > 0) ? rsqrtf((float)r1) : 0.0f;
        dv.z = (r2 > 0) ? rsqrtf((float)r2) : 0.0f;
        dv.w = (r3 > 0) ? rsqrtf((float)r3) : 0.0f;
        ((float4*)dis)[w] = dv;
        s = c0 + c1 + c2 + c3;
    }
#pragma unroll
    for (int d = 32; d > 0; d >>= 1) s += __shfl_down(s, d, 64);
    int lane = threadIdx.x & 63, wv = threadIdx.x >> 6;
    if (lane == 0) wsum[wv] = s;
    __syncthreads();
    if (threadIdx.x == 0) bsum[blockIdx.x] = wsum[0] + wsum[1] + wsum[2] + wsum[3];
}

// grid (G): local exclusive scan + inline cross-block base (wave 0 scans the
// G<=64 bsums redundantly per block).
__global__ __launch_bounds__(256) void scan_final_kernel(const int* __restrict__ cnt,
                                                         const int* __restrict__ bsum,
                                                         int* __restrict__ offs,
                                                         int n, int G) {
    __shared__ int wsum[4];
    __shared__ int sblock;
    int base = blockIdx.x * SCAN_CHUNK;
    int tid = threadIdx.x;
    const int PT = SCAN_CHUNK / 256;
    int v[PT];
    int s = 0;
#pragma unroll
    for (int i = 0; i < PT; i++) {
        int g = base + tid * PT + i;
        v[i] = (g < n) ? cnt[g] : 0;
        s += v[i];
    }
    int local_sum = s;
    int lane = tid & 63, w = tid >> 6;
#pragma unroll
    for (int d = 1; d < 64; d <<= 1) {
        int t = __shfl_up(s, d, 64);
        if (lane >= d) s += t;
    }
    if (lane == 63) wsum[w] = s;
    if (tid < 64) {
        int bv = (tid < G) ? bsum[tid] : 0;
        int bs = bv;
#pragma unroll
        for (int d = 1; d < 64; d <<= 1) {
            int t = __shfl_up(bs, d, 64);
            if (tid >= d) bs += t;
        }
        if (tid == blockIdx.x) sblock = bs - bv;            // exclusive base
        if (tid == 63 && blockIdx.x == G - 1) offs[n] = bs; // grand total
    }
    __syncthreads();
    int wbase = 0;
    for (int i = 0; i < w; i++) wbase += wsum[i];
    int run = sblock + wbase + (s - local_sum);
#pragma unroll
    for (int i = 0; i < PT; i++) {
        int g = base + tid * PT + i;
        if (g < n) offs[g] = run;
        run += v[i];
    }
}

// grid (CHUNKS, QUARTERS): LDS cursors (12.5KB, quarter node range) seeded
// with chunk_prefix + group-exclusive base. slot = offs[col] + byte(old).
// epack entry: row:u16 | norm:bf16. Edges outside the quarter are skipped.
// R19: unroll x4 -- batch 8 ei loads + 8 dis gathers (unconditional,
// L2-resident) before the predicated atomic/store phase.
__global__ __launch_bounds__(256) void scatter_kernel(const int* __restrict__ ei,
                                                      const float* __restrict__ dis,
                                                      const int* __restrict__ offs,
                                                      const unsigned* __restrict__ chpref,
                                                      const unsigned* __restrict__ gpref,
                                                      unsigned* __restrict__ epack,
                                                      int E, int CHSZ, int NW) {
    __shared__ unsigned cur[QWRD];
    int tid = threadIdx.x;
    int ch = blockIdx.x;
    int q = blockIdx.y;
    int wbase = q * QWRD;                          // word offset of this quarter
    int bin0 = q * QBINS;
    const unsigned* pf = chpref + (size_t)ch * LDSW + wbase;
    const unsigned* gb = gpref + (size_t)(ch / GS) * NW;
    for (int i = tid; i < QWRD; i += 256) {
        unsigned seed = pf[i];
        int w = wbase + i;
        if (w < NW) seed += gb[w];
        cur[i] = seed;
    }
    __syncthreads();
    int e0 = ch * CHSZ, e1 = min(e0 + CHSZ, E);
    int e = e0 + tid;
#define SC_PROC(rr, cc, ww)                                                    \
    if ((rr) != (cc)) {                                                        \
        int rb = (cc) - bin0;                                                  \
        if ((unsigned)rb < (unsigned)QBINS) {                                  \
            int wd = rb >> 2, sh = (rb & 3) * 8;                               \
            unsigned old = atomicAdd(&cur[wd], 1u << sh);                      \
            int slot = offs[cc] + (int)((old >> sh) & 0xFFu);                  \
            epack[slot] = (unsigned)(rr) |                                     \
                          ((unsigned)(unsigned short)f2bf(ww) << 16);          \
        }                                                                      \
    }
    for (; e + 768 < e1; e += 1024) {
        int r0 = ei[e],       c0 = ei[E + e];
        int r1 = ei[e + 256], c1 = ei[E + e + 256];
        int r2 = ei[e + 512], c2 = ei[E + e + 512];
        int r3 = ei[e + 768], c3 = ei[E + e + 768];
        float dr0 = dis[r0], dc0 = dis[c0];
        float dr1 = dis[r1], dc1 = dis[c1];
        float dr2 = dis[r2], dc2 = dis[c2];
        float dr3 = dis[r3], dc3 = dis[c3];
        float w0 = dr0 * dc0, w1 = dr1 * dc1, w2 = dr2 * dc2, w3 = dr3 * dc3;
        SC_PROC(r0, c0, w0);
        SC_PROC(r1, c1, w1);
        SC_PROC(r2, c2, w2);
        SC_PROC(r3, c3, w3);
    }
    for (; e < e1; e += 256) {
        int row = ei[e];
        int col = ei[E + e];
        float wgt = dis[row] * dis[col];
        SC_PROC(row, col, wgt);
    }
#undef SC_PROC
}

// ---------------- per-layer kernels ----------------------------------------

// hWb[r][j] = bf16( b[j] + sum_k h[r][k] * W[j][k] )  via 16x16x32 bf16 MFMA.
// Wave: 16 rows x 128 cols. C/D layout: col=lane&15, row=(lane>>4)*4+reg.
// Epilogue stages the bf16 tile in LDS then stores 4x contiguous 1KB/wave.
__global__ __launch_bounds__(256) void linear_mfma_kernel(
    const float* __restrict__ A, const unsigned short* __restrict__ Wb,
    const float* __restrict__ bias, unsigned short* __restrict__ hWb, int nrows) {
    __shared__ unsigned short stage[4][16 * 136];
    int wave = threadIdx.x >> 6;
    int lane = threadIdx.x & 63;
    int r0 = blockIdx.x * 64 + wave * 16;
    int m = lane & 15, q = lane >> 4;
    int rload = min(r0 + m, nrows - 1);
    const float4* h4 = (const float4*)A;

    f32x4 acc[8];
#pragma unroll
    for (int jt = 0; jt < 8; jt++) acc[jt] = (f32x4){0.f, 0.f, 0.f, 0.f};

#pragma unroll
    for (int k0 = 0; k0 < 128; k0 += 32) {
        int c0 = k0 + q * 8;
        float4 x0 = h4[rload * 32 + (c0 >> 2)];
        float4 x1 = h4[rload * 32 + (c0 >> 2) + 1];
        bf16x8 a;
        a[0] = f2bf(x0.x); a[1] = f2bf(x0.y); a[2] = f2bf(x0.z); a[3] = f2bf(x0.w);
        a[4] = f2bf(x1.x); a[5] = f2bf(x1.y); a[6] = f2bf(x1.z); a[7] = f2bf(x1.w);
#pragma unroll
        for (int jt = 0; jt < 8; jt++) {
            bf16x8 b = *(const bf16x8*)(Wb + (jt * 16 + m) * D_DIM + c0);
            acc[jt] = __builtin_amdgcn_mfma_f32_16x16x32_bf16(a, b, acc[jt], 0, 0, 0);
        }
    }

#pragma unroll
    for (int jt = 0; jt < 8; jt++) {
        float bv = bias[jt * 16 + m];
#pragma unroll
        for (int reg = 0; reg < 4; reg++)
            stage[wave][(q * 4 + reg) * 136 + jt * 16 + m] =
                (unsigned short)f2bf(acc[jt][reg] + bv);
    }
#pragma unroll
    for (int t = 0; t < 4; t++) {
        int rl = t * 4 + (lane >> 4);
        int gr = r0 + rl;
        if (gr < nrows) {
            uint4 v = *(const uint4*)&stage[wave][rl * 136 + (lane & 15) * 8];
            *(uint4*)&hWb[(size_t)gr * D_DIM + (lane & 15) * 8] = v;
        }
    }
}

// one wave per destination node; quad-row gathers: lane (g=lane>>4, s=lane&15)
// loads 16B (dims 8s..8s+7) of an edge row per dwordx4. 16 edges/round --
// group g takes slots i+g, i+4+g, i+8+g, i+12+g; 4 epack loads + 4 gathers
// issued as independent chains per round; ragged ends via index clamp +
// weight zeroing (R16: predication regressed; clamp dupes are free). fp32
// acc; shfl_xor(16|32) cross-group reduce; group-0 float4 epilogue
// h_out = h_prev + relu(acc).
__global__ __launch_bounds__(256) void agg_kernel(const int* __restrict__ offs,
                                                  const unsigned* __restrict__ epack,
                                                  const uint4* __restrict__ hW4,
                                                  const float* __restrict__ hprev,
                                                  float* __restrict__ hout, int n_nodes) {
    int node = (int)((blockIdx.x * blockDim.x + threadIdx.x) >> 6);
    int lane = threadIdx.x & 63;
    if (node >= n_nodes) return;
    int g = lane >> 4, s = lane & 15;

    int beg = offs[node];
    int end = offs[node + 1];

    float acc[8];
#pragma unroll
    for (int k = 0; k < 8; k++) acc[k] = 0.f;

    for (int i = beg; i < end; i += 16) {
        int last = end - 1;
        int i0 = i + g, i1 = i0 + 4, i2 = i0 + 8, i3 = i0 + 12;
        unsigned e0 = epack[min(i0, last)];
        unsigned e1 = epack[min(i1, last)];
        unsigned e2 = epack[min(i2, last)];
        unsigned e3 = epack[min(i3, last)];
        uint4 p0 = hW4[(e0 & 0xffffu) * 16 + s];
        uint4 p1 = hW4[(e1 & 0xffffu) * 16 + s];
        uint4 p2 = hW4[(e2 & 0xffffu) * 16 + s];
        uint4 p3 = hW4[(e3 & 0xffffu) * 16 + s];
        float w0 = (i0 < end) ? bf_hi(e0) : 0.f;
        float w1 = (i1 < end) ? bf_hi(e1) : 0.f;
        float w2 = (i2 < end) ? bf_hi(e2) : 0.f;
        float w3 = (i3 < end) ? bf_hi(e3) : 0.f;
        acc[0] = fmaf(w0, bf_lo(p0.x), acc[0]); acc[1] = fmaf(w0, bf_hi(p0.x), acc[1]);
        acc[2] = fmaf(w0, bf_lo(p0.y), acc[2]); acc[3] = fmaf(w0, bf_hi(p0.y), acc[3]);
        acc[4] = fmaf(w0, bf_lo(p0.z), acc[4]); acc[5] = fmaf(w0, bf_hi(p0.z), acc[5]);
        acc[6] = fmaf(w0, bf_lo(p0.w), acc[6]); acc[7] = fmaf(w0, bf_hi(p0.w), acc[7]);
        acc[0] = fmaf(w1, bf_lo(p1.x), acc[0]); acc[1] = fmaf(w1, bf_hi(p1.x), acc[1]);
        acc[2] = fmaf(w1, bf_lo(p1.y), acc[2]); acc[3] = fmaf(w1, bf_hi(p1.y), acc[3]);
        acc[4] = fmaf(w1, bf_lo(p1.z), acc[4]); acc[5] = fmaf(w1, bf_hi(p1.z), acc[5]);
        acc[6] = fmaf(w1, bf_lo(p1.w), acc[6]); acc[7] = fmaf(w1, bf_hi(p1.w), acc[7]);
        acc[0] = fmaf(w2, bf_lo(p2.x), acc[0]); acc[1] = fmaf(w2, bf_hi(p2.x), acc[1]);
        acc[2] = fmaf(w2, bf_lo(p2.y), acc[2]); acc[3] = fmaf(w2, bf_hi(p2.y), acc[3]);
        acc[4] = fmaf(w2, bf_lo(p2.z), acc[4]); acc[5] = fmaf(w2, bf_hi(p2.z), acc[5]);
        acc[6] = fmaf(w2, bf_lo(p2.w), acc[6]); acc[7] = fmaf(w2, bf_hi(p2.w), acc[7]);
        acc[0] = fmaf(w3, bf_lo(p3.x), acc[0]); acc[1] = fmaf(w3, bf_hi(p3.x), acc[1]);
        acc[2] = fmaf(w3, bf_lo(p3.y), acc[2]); acc[3] = fmaf(w3, bf_hi(p3.y), acc[3]);
        acc[4] = fmaf(w3, bf_lo(p3.z), acc[4]); acc[5] = fmaf(w3, bf_hi(p3.z), acc[5]);
        acc[6] = fmaf(w3, bf_lo(p3.w), acc[6]); acc[7] = fmaf(w3, bf_hi(p3.w), acc[7]);
    }

#pragma unroll
    for (int k = 0; k < 8; k++) {                   // sum the 4 groups
        acc[k] += __shfl_xor(acc[k], 16, 64);
        acc[k] += __shfl_xor(acc[k], 32, 64);
    }

    if (g == 0) {                                   // lanes 0..15 own dims 8s..8s+7
        const float4* hp4 = (const float4*)hprev;
        float4* ho4 = (float4*)hout;
        int idx = node * 32 + s * 2;
        float4 h0 = hp4[idx], h1 = hp4[idx + 1];
        float4 o0, o1;
        o0.x = h0.x + fmaxf(acc[0], 0.f); o0.y = h0.y + fmaxf(acc[1], 0.f);
        o0.z = h0.z + fmaxf(acc[2], 0.f); o0.w = h0.w + fmaxf(acc[3], 0.f);
        o1.x = h1.x + fmaxf(acc[4], 0.f); o1.y = h1.y + fmaxf(acc[5], 0.f);
        o1.z = h1.z + fmaxf(acc[6], 0.f); o1.w = h1.w + fmaxf(acc[7], 0.f);
        ho4[idx] = o0;
        ho4[idx + 1] = o1;
    }
}

// ---------------- launch ----------------------------------------------------

static inline size_t align_up(size_t x, size_t a) { return (x + a - 1) & ~(a - 1); }

extern "C" void kernel_launch(void* const* d_in, const int* in_sizes, int n_in,
                              void* d_out, int out_size, void* d_ws, size_t ws_size,
                              hipStream_t stream) {
    const float* x = (const float*)d_in[0];
    const int* ei = (const int*)d_in[1];
    const float* Wl[3] = {(const float*)d_in[2], (const float*)d_in[4], (const float*)d_in[6]};
    const float* bl[3] = {(const float*)d_in[3], (const float*)d_in[5], (const float*)d_in[7]};

    const int N = in_sizes[0] / D_DIM;                 // 50000 (requires N <= 4*LDSW, N < 65536)
    const int E = in_sizes[1] / 2;                     // 800000
    const int NW = N / 4;                              // 12500 packed words
    const int G = (N + SCAN_CHUNK - 1) / SCAN_CHUNK;   // 49 (must be <= 64)
    const int NWB = (NW + 255) / 256;                  // 49 word-blocks
    const int CHSZ = (E + CHUNKS - 1) / CHUNKS;        // 6250

    char* p = (char*)d_ws;
    int* col_cnt = (int*)p;            p += align_up((size_t)N * 4, 256);
    int* offs    = (int*)p;            p += align_up((size_t)(N + 1) * 4, 256);
    float* dis   = (float*)p;          p += align_up((size_t)N * 4, 256);
    int* bsum    = (int*)p;            p += align_up((size_t)64 * 4, 256);
    unsigned* partial_col = (unsigned*)p;  p += align_up((size_t)CHUNKS * LDSW * 4, 256);
    unsigned* partial_row = (unsigned*)p;  p += align_up((size_t)CHUNKS * LDSW * 4, 256);
    unsigned* gsum_col = (unsigned*)p; p += align_up((size_t)GROUPS * NW * 4, 256);
    unsigned* gsum_row = (unsigned*)p; p += align_up((size_t)GROUPS * NW * 4, 256);
    unsigned short* Wb = (unsigned short*)p;  p += align_up((size_t)3 * D_DIM * D_DIM * 2, 256);
    unsigned* epack = (unsigned*)p;    p += align_up((size_t)E * 4, 256);
    unsigned short* hWb = (unsigned short*)p;  p += align_up((size_t)N * D_DIM * 2, 256);
    (void)ws_size;

    int gemm_blocks = (N + 63) / 64;                   // 782
    int hist_gx = gemm_blocks;                         // covers CHUNKS and wcvt too

    hist_kernel<<<dim3(hist_gx, 6), 256, 0, stream>>>(ei, partial_col, partial_row,
                                                      Wl[0], Wl[1], Wl[2], Wb,
                                                      x, bl[0], hWb, N, E, CHSZ);
    group_prefix_kernel<<<dim3(NWB, GROUPS, 2), 256, 0, stream>>>(partial_col, partial_row,
                                                                  gsum_col, gsum_row, NW);
    cnt_dis_kernel<<<NWB, 256, 0, stream>>>(gsum_col, gsum_row, col_cnt, dis, bsum, NW);
    scan_final_kernel<<<G, 256, 0, stream>>>(col_cnt, bsum, offs, N, G);
    scatter_kernel<<<dim3(CHUNKS, QUARTERS), 256, 0, stream>>>(ei, dis, offs, partial_col,
                                                               gsum_col, epack, E, CHSZ, NW);

    const float* hprev = x;
    float* h = (float*)d_out;
    int agg_blocks = (N + 3) / 4;
    for (int l = 0; l < 3; l++) {
        if (l > 0)
            linear_mfma_kernel<<<gemm_blocks, 256, 0, stream>>>(hprev, Wb + l * 16384,
                                                                bl[l], hWb, N);
        agg_kernel<<<agg_blocks, 256, 0, stream>>>(offs, epack, (const uint4*)hWb, hprev, h, N);
        hprev = h;
    }
}

// Round 9
// 295.021 us; speedup vs baseline: 1.0305x; 1.0305x over previous
//
#include <hip/hip_runtime.h>
#include <hip/hip_bf16.h>

// GCN: 3 layers of  h = h + relu( segment_sum( norm * (h@W^T+b)[row], col ) )
// norm[e] = dis[row]*dis[col]*(row!=col), dis[v] = deg_row(v)>0 ? rsqrt(deg) : 0
// N=50000, D=128, E=800000. Harness compares in bf16 space (threshold 0.108):
// hW / GEMM inputs carried in bf16, accumulation fp32.
//
// R20: R19's strided unroll REVERTED (+10us regression -- compiler already
// pipelines the predicated-atomic loop; 2nd refutation of per-wave-ILP
// theory). New lever: VECTORIZED edge loads (G13) -- each thread owns 4
// consecutive edges via two int4 (dwordx4) loads, 4x fewer VMEM instructions
// at the 16B/lane coalescing sweet spot; processing stays in R18's proven
// predicated form. Applied to hist y=0..3 and scatter. CHSZ rounded up to a
// multiple of 4 (6252) for 16B alignment; scalar tail (empty here).
// R18 (kept): L0 GEMM fused into hist y=5 (-1 dispatch).
// R17 (kept): CHUNKS=128; scatter quarter-split (12.5KB); agg index-clamp.
// R15 (kept): hist half-split (25KB LDS).
// R12/R11 (kept): agg 16 edges/round quad-row gathers, shfl_xor reduce.
// Kept lessons: no cooperative fusion (R7); global atomics contention-bound
// (R14); predicated gathers lose to clamped in agg (R16); partials traffic
// not binding (R17); strided-load batching useless (R19).

#define D_DIM 128
#define SCAN_CHUNK 1024
#define CHUNKS 128         // edge chunks
#define GROUPS 8
#define GS (CHUNKS / GROUPS)   // 16 chunks per group
#define LDSW 12512         // packed words: 4 bins/word -> 50048 bins >= N
#define HALVES 2
#define HWRD (LDSW / HALVES)   // 6256 words per half (25KB LDS) -- hist
#define HBINS (HWRD * 4)       // 25024 bins per half
#define QUARTERS 4
#define QWRD (LDSW / QUARTERS) // 3128 words per quarter (12.5KB LDS) -- scatter
#define QBINS (QWRD * 4)       // 12512 bins per quarter

typedef __attribute__((ext_vector_type(8))) short bf16x8;
typedef __attribute__((ext_vector_type(4))) float f32x4;

static __device__ __forceinline__ short f2bf(float f) {
    union { __hip_bfloat16 b; short s; } u;
    u.b = __float2bfloat16(f);
    return u.s;
}
static __device__ __forceinline__ float bf_lo(unsigned p) { return __uint_as_float(p << 16); }
static __device__ __forceinline__ float bf_hi(unsigned p) { return __uint_as_float(p & 0xffff0000u); }

// ---------------- CSR build (no global atomics, packed u8) ------------------

// grid (782, 6): y=0/1 col hist half 0/1, y=2/3 row hist half 0/1 (ch<CHUNKS),
// y=4 W->bf16 convert (<192 blocks), y=5 fused layer-0 linear (782 blocks).
// All paths share one 25KB LDS allocation (GEMM stages in an alias of it).
__global__ __launch_bounds__(256) void hist_kernel(const int* __restrict__ ei,
                                                   unsigned* __restrict__ partial_col,
                                                   unsigned* __restrict__ partial_row,
                                                   const float* __restrict__ W0,
                                                   const float* __restrict__ W1,
                                                   const float* __restrict__ W2,
                                                   unsigned short* __restrict__ Wb,
                                                   const float* __restrict__ x,
                                                   const float* __restrict__ b0,
                                                   unsigned short* __restrict__ hWb,
                                                   int nrows, int E, int CHSZ) {
    __shared__ unsigned hh[HWRD];
    int tid = threadIdx.x;
    if (blockIdx.y == 4) {                          // wcvt slice: 3*16384 elems
        int i = blockIdx.x * 256 + tid;
        if (i < 3 * D_DIM * D_DIM) {
            const float* W = (i < 16384) ? W0 : (i < 32768) ? W1 : W2;
            Wb[i] = (unsigned short)f2bf(W[i & 16383]);
        }
        return;
    }
    if (blockIdx.y == 5) {                          // fused layer-0 linear
        int wave = tid >> 6;
        int lane = tid & 63;
        int r0 = blockIdx.x * 64 + wave * 16;
        if (r0 >= nrows) return;
        int m = lane & 15, q = lane >> 4;
        int rload = min(r0 + m, nrows - 1);
        const float4* h4 = (const float4*)x;
        const float4* w4 = (const float4*)W0;

        f32x4 acc[8];
#pragma unroll
        for (int jt = 0; jt < 8; jt++) acc[jt] = (f32x4){0.f, 0.f, 0.f, 0.f};

#pragma unroll
        for (int k0 = 0; k0 < 128; k0 += 32) {
            int c0 = k0 + q * 8;
            float4 x0 = h4[rload * 32 + (c0 >> 2)];
            float4 x1 = h4[rload * 32 + (c0 >> 2) + 1];
            bf16x8 a;
            a[0] = f2bf(x0.x); a[1] = f2bf(x0.y); a[2] = f2bf(x0.z); a[3] = f2bf(x0.w);
            a[4] = f2bf(x1.x); a[5] = f2bf(x1.y); a[6] = f2bf(x1.z); a[7] = f2bf(x1.w);
#pragma unroll
            for (int jt = 0; jt < 8; jt++) {
                float4 w0v = w4[(jt * 16 + m) * 32 + (c0 >> 2)];
                float4 w1v = w4[(jt * 16 + m) * 32 + (c0 >> 2) + 1];
                bf16x8 b;
                b[0] = f2bf(w0v.x); b[1] = f2bf(w0v.y); b[2] = f2bf(w0v.z); b[3] = f2bf(w0v.w);
                b[4] = f2bf(w1v.x); b[5] = f2bf(w1v.y); b[6] = f2bf(w1v.z); b[7] = f2bf(w1v.w);
                acc[jt] = __builtin_amdgcn_mfma_f32_16x16x32_bf16(a, b, acc[jt], 0, 0, 0);
            }
        }
        unsigned short* stg = (unsigned short*)hh + wave * 16 * 136;  // LDS alias
#pragma unroll
        for (int jt = 0; jt < 8; jt++) {
            float bv = b0[jt * 16 + m];
#pragma unroll
            for (int reg = 0; reg < 4; reg++)
                stg[(q * 4 + reg) * 136 + jt * 16 + m] =
                    (unsigned short)f2bf(acc[jt][reg] + bv);
        }
#pragma unroll
        for (int t = 0; t < 4; t++) {
            int rl = t * 4 + (lane >> 4);
            int gr = r0 + rl;
            if (gr < nrows) {
                uint4 v = *(const uint4*)&stg[rl * 136 + (lane & 15) * 8];
                *(uint4*)&hWb[(size_t)gr * D_DIM + (lane & 15) * 8] = v;
            }
        }
        return;
    }
    int ch = blockIdx.x;
    if (ch >= CHUNKS) return;                       // grid.x widened for y>=4
    int docol = (blockIdx.y < 2);
    int half = blockIdx.y & 1;
    int bin0 = half * HBINS;
    for (int i = tid; i < HWRD; i += 256) hh[i] = 0u;
    __syncthreads();
    int e0 = ch * CHSZ, e1 = min(e0 + CHSZ, E);
    // R20: int4 edge loads -- thread owns 4 consecutive edges (16B/lane).
    // e0 is a multiple of 4 (CHSZ rounded up host-side) -> aligned.
    for (int eb = e0 + tid * 4; eb + 3 < e1; eb += 1024) {
        int4 rv = *(const int4*)(ei + eb);
        int4 cv = *(const int4*)(ei + E + eb);
        int b0_ = (docol ? cv.x : rv.x) - bin0;
        int b1_ = (docol ? cv.y : rv.y) - bin0;
        int b2_ = (docol ? cv.z : rv.z) - bin0;
        int b3_ = (docol ? cv.w : rv.w) - bin0;
        if (rv.x != cv.x && (unsigned)b0_ < (unsigned)HBINS)
            atomicAdd(&hh[b0_ >> 2], 1u << ((b0_ & 3) * 8));
        if (rv.y != cv.y && (unsigned)b1_ < (unsigned)HBINS)
            atomicAdd(&hh[b1_ >> 2], 1u << ((b1_ & 3) * 8));
        if (rv.z != cv.z && (unsigned)b2_ < (unsigned)HBINS)
            atomicAdd(&hh[b2_ >> 2], 1u << ((b2_ & 3) * 8));
        if (rv.w != cv.w && (unsigned)b3_ < (unsigned)HBINS)
            atomicAdd(&hh[b3_ >> 2], 1u << ((b3_ & 3) * 8));
    }
    {   // scalar tail: (e1-e0) % 4 edges (0 for this instance)
        int et = e0 + ((e1 - e0) & ~3);
        for (int e = et + tid; e < e1; e += 256) {
            int row = ei[e];
            int col = ei[E + e];
            if (row == col) continue;
            int rb = (docol ? col : row) - bin0;
            if ((unsigned)rb < (unsigned)HBINS)
                atomicAdd(&hh[rb >> 2], 1u << ((rb & 3) * 8));
        }
    }
    __syncthreads();
    unsigned* dst = (docol ? partial_col : partial_row) + (size_t)ch * LDSW + half * HWRD;
    for (int i = tid; i < HWRD; i += 256) dst[i] = hh[i];
}

// grid (ceil(NW/256), GROUPS, 2). z=0: in-place exclusive prefix of col counts
// over the group's GS chunks + group sum. z=1: row group sums only.
__global__ __launch_bounds__(256) void group_prefix_kernel(
    unsigned* __restrict__ partial_col, const unsigned* __restrict__ partial_row,
    unsigned* __restrict__ gsum_col, unsigned* __restrict__ gsum_row, int NW) {
    int w = blockIdx.x * 256 + threadIdx.x;
    if (w >= NW) return;
    int g = blockIdx.y;
    size_t base = (size_t)(g * GS) * LDSW + w;
    if (blockIdx.z == 0) {
        unsigned run = 0;
#pragma unroll 4
        for (int c = 0; c < GS; c++) {
            unsigned v = partial_col[base + (size_t)c * LDSW];
            partial_col[base + (size_t)c * LDSW] = run;
            run += v;
        }
        gsum_col[g * NW + w] = run;
    } else {
        unsigned run = 0;
#pragma unroll 4
        for (int c = 0; c < GS; c++) run += partial_row[base + (size_t)c * LDSW];
        gsum_row[g * NW + w] = run;
    }
}

// per packed word: sum the GROUPS group words -> col_cnt int4, dis float4,
// per-SCAN_CHUNK block sums, AND in-place exclusive prefix of gsum_col over
// groups (values already in registers -- replaces the gpref launch).
__global__ __launch_bounds__(256) void cnt_dis_kernel(
    unsigned* __restrict__ gsum_col, const unsigned* __restrict__ gsum_row,
    int* __restrict__ col_cnt, float* __restrict__ dis, int* __restrict__ bsum, int NW) {
    __shared__ int wsum[4];
    int w = blockIdx.x * 256 + threadIdx.x;
    int s = 0;
    if (w < NW) {
        unsigned wcv[GROUPS];
        unsigned clo = 0, chi = 0, rlo = 0, rhi = 0;
#pragma unroll
        for (int g = 0; g < GROUPS; g++) {
            unsigned wc = gsum_col[g * NW + w];
            unsigned wr = gsum_row[g * NW + w];
            wcv[g] = wc;
            clo += wc & 0x00FF00FFu; chi += (wc >> 8) & 0x00FF00FFu;
            rlo += wr & 0x00FF00FFu; rhi += (wr >> 8) & 0x00FF00FFu;
        }
        unsigned run = 0;
#pragma unroll
        for (int g = 0; g < GROUPS; g++) {         // exclusive prefix (packed u8)
            gsum_col[g * NW + w] = run;
            run += wcv[g];
        }
        int c0 = clo & 0xFFFF, c1 = chi & 0xFFFF, c2 = clo >> 16, c3 = chi >> 16;
        int r0 = rlo & 0xFFFF, r1 = rhi & 0xFFFF, r2 = rlo >> 16, r3 = rhi >> 16;
        ((int4*)col_cnt)[w] = make_int4(c0, c1, c2, c3);
        float4 dv;
        dv.x = (r0 > 0) ? rsqrtf((float)r0) : 0.0f;
        dv.y = (r1 > 0) ? rsqrtf((float)r1) : 0.0f;
        dv.z = (r2 > 0) ? rsqrtf((float)r2) : 0.0f;
        dv.w = (r3 > 0) ? rsqrtf((float)r3) : 0.0f;
        ((float4*)dis)[w] = dv;
        s = c0 + c1 + c2 + c3;
    }
#pragma unroll
    for (int d = 32; d > 0; d >>= 1) s += __shfl_down(s, d, 64);
    int lane = threadIdx.x & 63, wv = threadIdx.x >> 6;
    if (lane == 0) wsum[wv] = s;
    __syncthreads();
    if (threadIdx.x == 0) bsum[blockIdx.x] = wsum[0] + wsum[1] + wsum[2] + wsum[3];
}

// grid (G): local exclusive scan + inline cross-block base (wave 0 scans the
// G<=64 bsums redundantly per block).
__global__ __launch_bounds__(256) void scan_final_kernel(const int* __restrict__ cnt,
                                                         const int* __restrict__ bsum,
                                                         int* __restrict__ offs,
                                                         int n, int G) {
    __shared__ int wsum[4];
    __shared__ int sblock;
    int base = blockIdx.x * SCAN_CHUNK;
    int tid = threadIdx.x;
    const int PT = SCAN_CHUNK / 256;
    int v[PT];
    int s = 0;
#pragma unroll
    for (int i = 0; i < PT; i++) {
        int g = base + tid * PT + i;
        v[i] = (g < n) ? cnt[g] : 0;
        s += v[i];
    }
    int local_sum = s;
    int lane = tid & 63, w = tid >> 6;
#pragma unroll
    for (int d = 1; d < 64; d <<= 1) {
        int t = __shfl_up(s, d, 64);
        if (lane >= d) s += t;
    }
    if (lane == 63) wsum[w] = s;
    if (tid < 64) {
        int bv = (tid < G) ? bsum[tid] : 0;
        int bs = bv;
#pragma unroll
        for (int d = 1; d < 64; d <<= 1) {
            int t = __shfl_up(bs, d, 64);
            if (tid >= d) bs += t;
        }
        if (tid == blockIdx.x) sblock = bs - bv;            // exclusive base
        if (tid == 63 && blockIdx.x == G - 1) offs[n] = bs; // grand total
    }
    __syncthreads();
    int wbase = 0;
    for (int i = 0; i < w; i++) wbase += wsum[i];
    int run = sblock + wbase + (s - local_sum);
#pragma unroll
    for (int i = 0; i < PT; i++) {
        int g = base + tid * PT + i;
        if (g < n) offs[g] = run;
        run += v[i];
    }
}

// grid (CHUNKS, QUARTERS): LDS cursors (12.5KB, quarter node range) seeded
// with chunk_prefix + group-exclusive base. slot = offs[col] + byte(old).
// epack entry: row:u16 | norm:bf16. Edges outside the quarter are skipped.
// R20: int4 edge loads (4 consecutive edges/thread); processing unchanged.
__global__ __launch_bounds__(256) void scatter_kernel(const int* __restrict__ ei,
                                                      const float* __restrict__ dis,
                                                      const int* __restrict__ offs,
                                                      const unsigned* __restrict__ chpref,
                                                      const unsigned* __restrict__ gpref,
                                                      unsigned* __restrict__ epack,
                                                      int E, int CHSZ, int NW) {
    __shared__ unsigned cur[QWRD];
    int tid = threadIdx.x;
    int ch = blockIdx.x;
    int q = blockIdx.y;
    int wbase = q * QWRD;                          // word offset of this quarter
    int bin0 = q * QBINS;
    const unsigned* pf = chpref + (size_t)ch * LDSW + wbase;
    const unsigned* gb = gpref + (size_t)(ch / GS) * NW;
    for (int i = tid; i < QWRD; i += 256) {
        unsigned seed = pf[i];
        int w = wbase + i;
        if (w < NW) seed += gb[w];
        cur[i] = seed;
    }
    __syncthreads();
    int e0 = ch * CHSZ, e1 = min(e0 + CHSZ, E);
#define SC_PROC(rr, cc)                                                        \
    if ((rr) != (cc)) {                                                        \
        int rb = (cc) - bin0;                                                  \
        if ((unsigned)rb < (unsigned)QBINS) {                                  \
            float wgt = dis[rr] * dis[cc];                                     \
            int wd = rb >> 2, sh = (rb & 3) * 8;                               \
            unsigned old = atomicAdd(&cur[wd], 1u << sh);                      \
            int slot = offs[cc] + (int)((old >> sh) & 0xFFu);                  \
            epack[slot] = (unsigned)(rr) |                                     \
                          ((unsigned)(unsigned short)f2bf(wgt) << 16);         \
        }                                                                      \
    }
    for (int eb = e0 + tid * 4; eb + 3 < e1; eb += 1024) {
        int4 rv = *(const int4*)(ei + eb);
        int4 cv = *(const int4*)(ei + E + eb);
        SC_PROC(rv.x, cv.x);
        SC_PROC(rv.y, cv.y);
        SC_PROC(rv.z, cv.z);
        SC_PROC(rv.w, cv.w);
    }
    {   // scalar tail
        int et = e0 + ((e1 - e0) & ~3);
        for (int e = et + tid; e < e1; e += 256) {
            int row = ei[e];
            int col = ei[E + e];
            SC_PROC(row, col);
        }
    }
#undef SC_PROC
}

// ---------------- per-layer kernels ----------------------------------------

// hWb[r][j] = bf16( b[j] + sum_k h[r][k] * W[j][k] )  via 16x16x32 bf16 MFMA.
// Wave: 16 rows x 128 cols. C/D layout: col=lane&15, row=(lane>>4)*4+reg.
// Epilogue stages the bf16 tile in LDS then stores 4x contiguous 1KB/wave.
__global__ __launch_bounds__(256) void linear_mfma_kernel(
    const float* __restrict__ A, const unsigned short* __restrict__ Wb,
    const float* __restrict__ bias, unsigned short* __restrict__ hWb, int nrows) {
    __shared__ unsigned short stage[4][16 * 136];
    int wave = threadIdx.x >> 6;
    int lane = threadIdx.x & 63;
    int r0 = blockIdx.x * 64 + wave * 16;
    int m = lane & 15, q = lane >> 4;
    int rload = min(r0 + m, nrows - 1);
    const float4* h4 = (const float4*)A;

    f32x4 acc[8];
#pragma unroll
    for (int jt = 0; jt < 8; jt++) acc[jt] = (f32x4){0.f, 0.f, 0.f, 0.f};

#pragma unroll
    for (int k0 = 0; k0 < 128; k0 += 32) {
        int c0 = k0 + q * 8;
        float4 x0 = h4[rload * 32 + (c0 >> 2)];
        float4 x1 = h4[rload * 32 + (c0 >> 2) + 1];
        bf16x8 a;
        a[0] = f2bf(x0.x); a[1] = f2bf(x0.y); a[2] = f2bf(x0.z); a[3] = f2bf(x0.w);
        a[4] = f2bf(x1.x); a[5] = f2bf(x1.y); a[6] = f2bf(x1.z); a[7] = f2bf(x1.w);
#pragma unroll
        for (int jt = 0; jt < 8; jt++) {
            bf16x8 b = *(const bf16x8*)(Wb + (jt * 16 + m) * D_DIM + c0);
            acc[jt] = __builtin_amdgcn_mfma_f32_16x16x32_bf16(a, b, acc[jt], 0, 0, 0);
        }
    }

#pragma unroll
    for (int jt = 0; jt < 8; jt++) {
        float bv = bias[jt * 16 + m];
#pragma unroll
        for (int reg = 0; reg < 4; reg++)
            stage[wave][(q * 4 + reg) * 136 + jt * 16 + m] =
                (unsigned short)f2bf(acc[jt][reg] + bv);
    }
#pragma unroll
    for (int t = 0; t < 4; t++) {
        int rl = t * 4 + (lane >> 4);
        int gr = r0 + rl;
        if (gr < nrows) {
            uint4 v = *(const uint4*)&stage[wave][rl * 136 + (lane & 15) * 8];
            *(uint4*)&hWb[(size_t)gr * D_DIM + (lane & 15) * 8] = v;
        }
    }
}

// one wave per destination node; quad-row gathers: lane (g=lane>>4, s=lane&15)
// loads 16B (dims 8s..8s+7) of an edge row per dwordx4. 16 edges/round --
// group g takes slots i+g, i+4+g, i+8+g, i+12+g; 4 epack loads + 4 gathers
// issued as independent chains per round; ragged ends via index clamp +
// weight zeroing (R16: predication regressed; clamp dupes are free). fp32
// acc; shfl_xor(16|32) cross-group reduce; group-0 float4 epilogue
// h_out = h_prev + relu(acc).
__global__ __launch_bounds__(256) void agg_kernel(const int* __restrict__ offs,
                                                  const unsigned* __restrict__ epack,
                                                  const uint4* __restrict__ hW4,
                                                  const float* __restrict__ hprev,
                                                  float* __restrict__ hout, int n_nodes) {
    int node = (int)((blockIdx.x * blockDim.x + threadIdx.x) >> 6);
    int lane = threadIdx.x & 63;
    if (node >= n_nodes) return;
    int g = lane >> 4, s = lane & 15;

    int beg = offs[node];
    int end = offs[node + 1];

    float acc[8];
#pragma unroll
    for (int k = 0; k < 8; k++) acc[k] = 0.f;

    for (int i = beg; i < end; i += 16) {
        int last = end - 1;
        int i0 = i + g, i1 = i0 + 4, i2 = i0 + 8, i3 = i0 + 12;
        unsigned e0 = epack[min(i0, last)];
        unsigned e1 = epack[min(i1, last)];
        unsigned e2 = epack[min(i2, last)];
        unsigned e3 = epack[min(i3, last)];
        uint4 p0 = hW4[(e0 & 0xffffu) * 16 + s];
        uint4 p1 = hW4[(e1 & 0xffffu) * 16 + s];
        uint4 p2 = hW4[(e2 & 0xffffu) * 16 + s];
        uint4 p3 = hW4[(e3 & 0xffffu) * 16 + s];
        float w0 = (i0 < end) ? bf_hi(e0) : 0.f;
        float w1 = (i1 < end) ? bf_hi(e1) : 0.f;
        float w2 = (i2 < end) ? bf_hi(e2) : 0.f;
        float w3 = (i3 < end) ? bf_hi(e3) : 0.f;
        acc[0] = fmaf(w0, bf_lo(p0.x), acc[0]); acc[1] = fmaf(w0, bf_hi(p0.x), acc[1]);
        acc[2] = fmaf(w0, bf_lo(p0.y), acc[2]); acc[3] = fmaf(w0, bf_hi(p0.y), acc[3]);
        acc[4] = fmaf(w0, bf_lo(p0.z), acc[4]); acc[5] = fmaf(w0, bf_hi(p0.z), acc[5]);
        acc[6] = fmaf(w0, bf_lo(p0.w), acc[6]); acc[7] = fmaf(w0, bf_hi(p0.w), acc[7]);
        acc[0] = fmaf(w1, bf_lo(p1.x), acc[0]); acc[1] = fmaf(w1, bf_hi(p1.x), acc[1]);
        acc[2] = fmaf(w1, bf_lo(p1.y), acc[2]); acc[3] = fmaf(w1, bf_hi(p1.y), acc[3]);
        acc[4] = fmaf(w1, bf_lo(p1.z), acc[4]); acc[5] = fmaf(w1, bf_hi(p1.z), acc[5]);
        acc[6] = fmaf(w1, bf_lo(p1.w), acc[6]); acc[7] = fmaf(w1, bf_hi(p1.w), acc[7]);
        acc[0] = fmaf(w2, bf_lo(p2.x), acc[0]); acc[1] = fmaf(w2, bf_hi(p2.x), acc[1]);
        acc[2] = fmaf(w2, bf_lo(p2.y), acc[2]); acc[3] = fmaf(w2, bf_hi(p2.y), acc[3]);
        acc[4] = fmaf(w2, bf_lo(p2.z), acc[4]); acc[5] = fmaf(w2, bf_hi(p2.z), acc[5]);
        acc[6] = fmaf(w2, bf_lo(p2.w), acc[6]); acc[7] = fmaf(w2, bf_hi(p2.w), acc[7]);
        acc[0] = fmaf(w3, bf_lo(p3.x), acc[0]); acc[1] = fmaf(w3, bf_hi(p3.x), acc[1]);
        acc[2] = fmaf(w3, bf_lo(p3.y), acc[2]); acc[3] = fmaf(w3, bf_hi(p3.y), acc[3]);
        acc[4] = fmaf(w3, bf_lo(p3.z), acc[4]); acc[5] = fmaf(w3, bf_hi(p3.z), acc[5]);
        acc[6] = fmaf(w3, bf_lo(p3.w), acc[6]); acc[7] = fmaf(w3, bf_hi(p3.w), acc[7]);
    }

#pragma unroll
    for (int k = 0; k < 8; k++) {                   // sum the 4 groups
        acc[k] += __shfl_xor(acc[k], 16, 64);
        acc[k] += __shfl_xor(acc[k], 32, 64);
    }

    if (g == 0) {                                   // lanes 0..15 own dims 8s..8s+7
        const float4* hp4 = (const float4*)hprev;
        float4* ho4 = (float4*)hout;
        int idx = node * 32 + s * 2;
        float4 h0 = hp4[idx], h1 = hp4[idx + 1];
        float4 o0, o1;
        o0.x = h0.x + fmaxf(acc[0], 0.f); o0.y = h0.y + fmaxf(acc[1], 0.f);
        o0.z = h0.z + fmaxf(acc[2], 0.f); o0.w = h0.w + fmaxf(acc[3], 0.f);
        o1.x = h1.x + fmaxf(acc[4], 0.f); o1.y = h1.y + fmaxf(acc[5], 0.f);
        o1.z = h1.z + fmaxf(acc[6], 0.f); o1.w = h1.w + fmaxf(acc[7], 0.f);
        ho4[idx] = o0;
        ho4[idx + 1] = o1;
    }
}

// ---------------- launch ----------------------------------------------------

static inline size_t align_up(size_t x, size_t a) { return (x + a - 1) & ~(a - 1); }

extern "C" void kernel_launch(void* const* d_in, const int* in_sizes, int n_in,
                              void* d_out, int out_size, void* d_ws, size_t ws_size,
                              hipStream_t stream) {
    const float* x = (const float*)d_in[0];
    const int* ei = (const int*)d_in[1];
    const float* Wl[3] = {(const float*)d_in[2], (const float*)d_in[4], (const float*)d_in[6]};
    const float* bl[3] = {(const float*)d_in[3], (const float*)d_in[5], (const float*)d_in[7]};

    const int N = in_sizes[0] / D_DIM;                 // 50000 (requires N <= 4*LDSW, N < 65536)
    const int E = in_sizes[1] / 2;                     // 800000 (multiple of 4 for int4 loads)
    const int NW = N / 4;                              // 12500 packed words
    const int G = (N + SCAN_CHUNK - 1) / SCAN_CHUNK;   // 49 (must be <= 64)
    const int NWB = (NW + 255) / 256;                  // 49 word-blocks
    const int CHSZ = (((E + CHUNKS - 1) / CHUNKS) + 3) & ~3;   // 6252 (16B-aligned chunks)

    char* p = (char*)d_ws;
    int* col_cnt = (int*)p;            p += align_up((size_t)N * 4, 256);
    int* offs    = (int*)p;            p += align_up((size_t)(N + 1) * 4, 256);
    float* dis   = (float*)p;          p += align_up((size_t)N * 4, 256);
    int* bsum    = (int*)p;            p += align_up((size_t)64 * 4, 256);
    unsigned* partial_col = (unsigned*)p;  p += align_up((size_t)CHUNKS * LDSW * 4, 256);
    unsigned* partial_row = (unsigned*)p;  p += align_up((size_t)CHUNKS * LDSW * 4, 256);
    unsigned* gsum_col = (unsigned*)p; p += align_up((size_t)GROUPS * NW * 4, 256);
    unsigned* gsum_row = (unsigned*)p; p += align_up((size_t)GROUPS * NW * 4, 256);
    unsigned short* Wb = (unsigned short*)p;  p += align_up((size_t)3 * D_DIM * D_DIM * 2, 256);
    unsigned* epack = (unsigned*)p;    p += align_up((size_t)E * 4, 256);
    unsigned short* hWb = (unsigned short*)p;  p += align_up((size_t)N * D_DIM * 2, 256);
    (void)ws_size;

    int gemm_blocks = (N + 63) / 64;                   // 782
    int hist_gx = gemm_blocks;                         // covers CHUNKS and wcvt too

    hist_kernel<<<dim3(hist_gx, 6), 256, 0, stream>>>(ei, partial_col, partial_row,
                                                      Wl[0], Wl[1], Wl[2], Wb,
                                                      x, bl[0], hWb, N, E, CHSZ);
    group_prefix_kernel<<<dim3(NWB, GROUPS, 2), 256, 0, stream>>>(partial_col, partial_row,
                                                                  gsum_col, gsum_row, NW);
    cnt_dis_kernel<<<NWB, 256, 0, stream>>>(gsum_col, gsum_row, col_cnt, dis, bsum, NW);
    scan_final_kernel<<<G, 256, 0, stream>>>(col_cnt, bsum, offs, N, G);
    scatter_kernel<<<dim3(CHUNKS, QUARTERS), 256, 0, stream>>>(ei, dis, offs, partial_col,
                                                               gsum_col, epack, E, CHSZ, NW);

    const float* hprev = x;
    float* h = (float*)d_out;
    int agg_blocks = (N + 3) / 4;
    for (int l = 0; l < 3; l++) {
        if (l > 0)
            linear_mfma_kernel<<<gemm_blocks, 256, 0, stream>>>(hprev, Wb + l * 16384,
                                                                bl[l], hWb, N);
        agg_kernel<<<agg_blocks, 256, 0, stream>>>(offs, epack, (const uint4*)hWb, hprev, h, N);
        hprev = h;
    }
}